// Round 13
// baseline (396.889 us; speedup 1.0000x reference)
//
#include <hip/hip_runtime.h>
#include <stdint.h>

typedef __attribute__((ext_vector_type(8))) short short8;
typedef __attribute__((ext_vector_type(4))) float floatx4;

#define EMB 768
#define DKV 256
#define NB  8
#define NS  2048

__device__ __forceinline__ float b2f(unsigned short u) {
  union { unsigned int i; float f; } v; v.i = ((unsigned int)u) << 16; return v.f;
}
__device__ __forceinline__ unsigned short f2b(float f) {
  union { float f; unsigned int i; } v; v.f = f;
  return (unsigned short)((v.i + 0x7FFFu + ((v.i >> 16) & 1u)) >> 16);
}

__device__ __forceinline__ short8 load8x(const void* p, size_t e, int f32) {
  short8 r;
  if (f32) {
    const float* f = (const float*)p + e;
    float4 a = *(const float4*)f;
    float4 b = *(const float4*)(f + 4);
    r[0] = (short)f2b(a.x); r[1] = (short)f2b(a.y);
    r[2] = (short)f2b(a.z); r[3] = (short)f2b(a.w);
    r[4] = (short)f2b(b.x); r[5] = (short)f2b(b.y);
    r[6] = (short)f2b(b.z); r[7] = (short)f2b(b.w);
  } else {
    r = *(const short8*)((const unsigned short*)p + e);
  }
  return r;
}
__device__ __forceinline__ float loadf(const void* p, size_t e, int f32) {
  return f32 ? ((const float*)p)[e] : b2f(((const unsigned short*)p)[e]);
}

// Async global->LDS DMA, 16B per lane; LDS dest = wave-uniform base + lane*16.
__device__ __forceinline__ void gl_lds16(const void* g, void* l) {
  __builtin_amdgcn_global_load_lds(
      (const __attribute__((address_space(1))) void*)g,
      (__attribute__((address_space(3))) void*)l, 16, 0, 0);
}

// ---------------------------------------------------------------------------
__global__ __launch_bounds__(256) void detect_kernel(
    const unsigned short* __restrict__ x, int* __restrict__ flag) {
  __shared__ int cnt;
  if (threadIdx.x == 0) cnt = 0;
  __syncthreads();
  int bad = 0;
  for (int i = threadIdx.x; i < 1024; i += 256) {
    float v = b2f(x[i]);
    if (!(fabsf(v) <= 1e4f)) bad++;
  }
  atomicAdd(&cnt, bad);
  __syncthreads();
  if (threadIdx.x == 0) {
    flag[0] = (cnt > 16) ? 1 : 0;   // real dtype flag (biases, outputs)
    flag[1] = 0;                    // constant bf16 flag for converted-X path
  }
}

// ---------------------------------------------------------------------------
// Merged prep kernel, 1D grid of 3840 blocks:
//   [0,1728)    WT tile transposes: WT[slab*256+d][k] = W[t][h][k][d]
//   [1728,2304) W0T tile transposes
//   [2304,3840) X -> bf16 conversion into Xb (only if do_x)
// ---------------------------------------------------------------------------
__global__ __launch_bounds__(256) void repack_all(
    const void* __restrict__ Wq, const void* __restrict__ Wk,
    const void* __restrict__ Wv, const void* __restrict__ W0,
    const void* __restrict__ X,
    unsigned short* __restrict__ WT, unsigned short* __restrict__ W0T,
    unsigned short* __restrict__ Xb,
    const int* __restrict__ flag, int do_x) {
  __shared__ unsigned short tile[32][33];
  const int f32 = *flag;
  const int tid = threadIdx.x;
  const int b = blockIdx.x;

  if (b < 1728) {
    const int slab = b / 192;            // 0..8
    const int rem = b - slab * 192;
    const int k0 = (rem % 24) * 32, d0 = (rem / 24) * 32;
    const int t = slab / 3, h = slab - t * 3;
    const void* Wsrc = (t == 0) ? Wq : ((t == 1) ? Wk : Wv);
#pragma unroll
    for (int rr = 0; rr < 4; ++rr) {
      int ki = rr * 8 + (tid >> 5), di = tid & 31;
      tile[ki][di] = f2b(loadf(Wsrc, (size_t)(h * EMB + k0 + ki) * DKV + d0 + di, f32));
    }
    __syncthreads();
#pragma unroll
    for (int rr = 0; rr < 4; ++rr) {
      int di = rr * 8 + (tid >> 5), ki = tid & 31;
      WT[(size_t)(slab * 256 + d0 + di) * EMB + k0 + ki] = tile[ki][di];
    }
  } else if (b < 2304) {
    const int bb = b - 1728;             // 0..575
    const int k0 = (bb % 24) * 32, o0 = (bb / 24) * 32;
#pragma unroll
    for (int rr = 0; rr < 4; ++rr) {
      int ki = rr * 8 + (tid >> 5), oi = tid & 31;
      tile[ki][oi] = f2b(loadf(W0, (size_t)(k0 + ki) * EMB + o0 + oi, f32));
    }
    __syncthreads();
#pragma unroll
    for (int rr = 0; rr < 4; ++rr) {
      int oi = rr * 8 + (tid >> 5), ki = tid & 31;
      W0T[(size_t)(o0 + oi) * EMB + k0 + ki] = tile[ki][oi];
    }
  } else {
    if (!do_x) return;
    const int bb = b - 2304;             // 0..1535; 1536*1024 short8 = 12.58M elems
#pragma unroll
    for (int i = 0; i < 4; ++i) {
      size_t e = ((size_t)bb * 1024 + i * 256 + tid) * 8;
      short8 v = load8x(X, e, f32);
      *(short8*)&Xb[e] = v;
    }
  }
}

// ---------------------------------------------------------------------------
// Fused K+V projection GEMM, 128 rows x (128 K-cols + 128 V-cols),
// T14-pipelined reg staging (r8-measured best; r9's gload_lds was neutral).
// ---------------------------------------------------------------------------
__global__ __launch_bounds__(256, 2) void kv_gemm(
    const void* __restrict__ Xs, const unsigned short* __restrict__ WT,
    const void* __restrict__ bk, const void* __restrict__ bv,
    unsigned short* __restrict__ Kb, unsigned short* __restrict__ Vtb,
    const int* __restrict__ xflag, const int* __restrict__ dflag) {
  __shared__ __align__(16) unsigned short As[128 * 40];
  __shared__ __align__(16) unsigned short BsK[128 * 40];
  __shared__ __align__(16) unsigned short BsV[128 * 40];
  const int xf32 = *xflag;
  const int f32 = *dflag;
  const int tid = threadIdx.x;
  const int wave = tid >> 6, lane = tid & 63, quad = lane >> 4, l15 = lane & 15;
  const int wm = wave >> 1, wn = wave & 1;
  const int row0 = blockIdx.y * 128;
  const int cb = blockIdx.x * 128;       // 0..640, col offset within each slab

  floatx4 accK[4][4], accV[4][4];
  for (int m = 0; m < 4; ++m)
    for (int n = 0; n < 4; ++n) { accK[m][n] = (floatx4)0.0f; accV[m][n] = (floatx4)0.0f; }

  const size_t arow0 = (size_t)row0 * EMB;
  const unsigned short* BbK = WT + (size_t)(768 + cb) * EMB;
  const unsigned short* BbV = WT + (size_t)(1536 + cb) * EMB;

  short8 va[2], vk[2], vv[2];
#pragma unroll
  for (int i = 0; i < 2; ++i) {           // prologue: k0 = 0
    int idx = i * 256 + tid;
    int r = idx >> 2, kp = (idx & 3) << 3;
    va[i] = load8x(Xs, arow0 + (size_t)r * EMB + kp, xf32);
    vk[i] = *(const short8*)(BbK + (size_t)r * EMB + kp);
    vv[i] = *(const short8*)(BbV + (size_t)r * EMB + kp);
  }

  for (int k0 = 0; k0 < EMB; k0 += 32) {
    __syncthreads();
#pragma unroll
    for (int i = 0; i < 2; ++i) {
      int idx = i * 256 + tid;
      int off = (idx >> 2) * 40 + (idx & 3) * 8;
      *(short8*)&As[off] = va[i];
      *(short8*)&BsK[off] = vk[i];
      *(short8*)&BsV[off] = vv[i];
    }
    if (k0 + 32 < EMB) {                  // issue next-tile loads
      const int kn = k0 + 32;
#pragma unroll
      for (int i = 0; i < 2; ++i) {
        int idx = i * 256 + tid;
        int r = idx >> 2, kp = (idx & 3) << 3;
        va[i] = load8x(Xs, arow0 + (size_t)r * EMB + kn + kp, xf32);
        vk[i] = *(const short8*)(BbK + (size_t)r * EMB + kn + kp);
        vv[i] = *(const short8*)(BbV + (size_t)r * EMB + kn + kp);
      }
    }
    __syncthreads();
    short8 af[4], bk4[4], bv4[4];
#pragma unroll
    for (int m = 0; m < 4; ++m)
      af[m] = *(const short8*)&As[(wm * 64 + m * 16 + l15) * 40 + quad * 8];
#pragma unroll
    for (int n = 0; n < 4; ++n) {
      bk4[n] = *(const short8*)&BsK[(wn * 64 + n * 16 + l15) * 40 + quad * 8];
      bv4[n] = *(const short8*)&BsV[(wn * 64 + n * 16 + l15) * 40 + quad * 8];
    }
    __builtin_amdgcn_s_setprio(1);
#pragma unroll
    for (int n = 0; n < 4; ++n)
#pragma unroll
      for (int m = 0; m < 4; ++m) {
        accK[m][n] = __builtin_amdgcn_mfma_f32_16x16x32_bf16(af[m], bk4[n], accK[m][n], 0, 0, 0);
        accV[m][n] = __builtin_amdgcn_mfma_f32_16x16x32_bf16(af[m], bv4[n], accV[m][n], 0, 0, 0);
      }
    __builtin_amdgcn_s_setprio(0);
  }

  const int h = cb >> 8;
  const int dbase = cb & 255;

  // K epilogue: [bh][n][d]
#pragma unroll
  for (int n = 0; n < 4; ++n) {
    const int cc = wn * 64 + n * 16 + l15;
    const float bvv = loadf(bk, h * 256 + dbase + cc, f32);
    const int d = dbase + cc;
#pragma unroll
    for (int m = 0; m < 4; ++m) {
      const int rbase = row0 + wm * 64 + m * 16 + quad * 4;
#pragma unroll
      for (int r = 0; r < 4; ++r) {
        const int row = rbase + r;
        const int bb = row >> 11, nn = row & 2047;
        Kb[((size_t)(bb * 3 + h) * 2048 + nn) * 256 + d] = f2b(accK[m][n][r] + bvv);
      }
    }
  }
  // V epilogue: transposed [bh][d][n]
#pragma unroll
  for (int n = 0; n < 4; ++n) {
    const int cc = wn * 64 + n * 16 + l15;
    const float bvv = loadf(bv, h * 256 + dbase + cc, f32);
    const int d = dbase + cc;
#pragma unroll
    for (int m = 0; m < 4; ++m) {
      const int rbase = row0 + wm * 64 + m * 16 + quad * 4;
      const int bb = rbase >> 11, nn = rbase & 2047;
      const size_t base = ((size_t)(bb * 3 + h) * 256 + d) * 2048 + nn;
      uint2 val;
      val.x = (uint32_t)f2b(accV[m][n][0] + bvv) | ((uint32_t)f2b(accV[m][n][1] + bvv) << 16);
      val.y = (uint32_t)f2b(accV[m][n][2] + bvv) | ((uint32_t)f2b(accV[m][n][3] + bvv) << 16);
      *(uint2*)(Vtb + base) = val;
    }
  }
}

// ---------------------------------------------------------------------------
// Fused Q-projection + flash attention, 64 q-rows/block.
// Phase Q: gl_lds double-buffered ping-pong (r12).
// Phase A: Ks DOUBLE-BUFFERED 2-ahead K prefetch:
//   - K(t+2) issued after B1(t) into the Ks buffer QK(t) just finished;
//     drained a FULL TILE later at B1(t+1) -> K latency fully hidden.
//   - B2 is a RAW s_barrier (no vmem drain): every wave's PV ds_reads are
//     complete by arrival (MFMA register dep), and the only in-flight DMA
//     (K) targets a buffer nobody reads. V(t+1) issued after B2, drained at
//     B1(t+1) as before.
// LDS = 53 KB (2xKs 16KB + Vts 16KB + Ps 5KB); 3 x 54272 B = 159 KB <= 160.
// ---------------------------------------------------------------------------
__global__ __launch_bounds__(256, 3) void flash_fused(
    const void* __restrict__ Xs, const unsigned short* __restrict__ WT,
    const void* __restrict__ bq,
    const unsigned short* __restrict__ Kb, const unsigned short* __restrict__ Vtb,
    unsigned short* __restrict__ Ob,
    const int* __restrict__ xflag, const int* __restrict__ dflag) {
  __shared__ __align__(16) unsigned short smem[27136];  // 53 KB
  // phase Q dbuf: A0 0..2048, A1 2048..4096, B0 4096..12288, B1 12288..20480
  unsigned short* Qs  = smem;           // phase Q epilogue: [64][264] (0..16896) ALIASES bufs
  // phase A: Ks0 0..8192, Ks1 8192..16384, Vts 16384..24576, Ps 24576..27136
  unsigned short* Vts = smem + 16384;   // [256][32] linear swz
  unsigned short* Ps  = smem + 24576;   // [64][40]

  const int xf32 = *xflag;
  const int f32 = *dflag;
  const int tid = threadIdx.x;
  const int wave = tid >> 6, lane = tid & 63, quad = lane >> 4, l15 = lane & 15;
  const int bh = blockIdx.x;            // bh fastest; 24%8==0 -> per-bh K/V XCD-local
  const int bb = bh / 3, hh = bh - bb * 3;
  const int q0 = blockIdx.y * 64;

  short8 qf[8];

  // ---------------- Phase Q: project one 64x256 Q strip --------------------
  {
    const size_t xrow0 = (size_t)bb * NS + q0;
    floatx4 qacc[4][4];
    for (int m = 0; m < 4; ++m)
      for (int n = 0; n < 4; ++n) qacc[m][n] = (floatx4)0.0f;

    const int srow = lane >> 2;          // 0..15 within a 16-row 1KB segment
    const int sch  = lane & 3;           // physical 16B chunk within 64B row
    const unsigned short* Wb = WT + (size_t)hh * 256 * EMB;

    // prologue: stage k0 = 0 into buffer 0
    {
      if (!xf32) {
        const int arow = wave * 16 + srow;
        const int asc = sch ^ ((arow >> 1) & 3);
        gl_lds16((const unsigned short*)Xs + (xrow0 + arow) * EMB + asc * 8,
                 &smem[wave * 512]);
      } else {
        int row = tid >> 2, pch = tid & 3;
        int gsc = pch ^ ((row >> 1) & 3);
        short8 v = load8x(Xs, (xrow0 + row) * EMB + gsc * 8, 1);
        *(short8*)&smem[row * 32 + pch * 8] = v;
      }
#pragma unroll
      for (int i = 0; i < 4; ++i) {
        const int L = wave * 4 + i;
        const int brow = L * 16 + srow;
        const int bsc = sch ^ ((brow >> 1) & 3);
        gl_lds16(Wb + (size_t)brow * EMB + bsc * 8, &smem[4096 + L * 512]);
      }
    }
    __syncthreads();   // buffer 0 ready

    int p = 0;
    for (int k0 = 0; k0 < EMB; k0 += 32) {
      unsigned short* Ac = smem + (p ? 2048 : 0);
      unsigned short* Bc = smem + 4096 + (p ? 8192 : 0);
      if (k0 + 32 < EMB) {               // stage next step into other buffer
        unsigned short* An = smem + (p ? 0 : 2048);
        unsigned short* Bn = smem + 4096 + (p ? 0 : 8192);
        const int kn = k0 + 32;
        if (!xf32) {
          const int arow = wave * 16 + srow;
          const int asc = sch ^ ((arow >> 1) & 3);
          gl_lds16((const unsigned short*)Xs + (xrow0 + arow) * EMB + kn + asc * 8,
                   &An[wave * 512]);
        } else {
          int row = tid >> 2, pch = tid & 3;
          int gsc = pch ^ ((row >> 1) & 3);
          short8 v = load8x(Xs, (xrow0 + row) * EMB + kn + gsc * 8, 1);
          *(short8*)&An[row * 32 + pch * 8] = v;
        }
#pragma unroll
        for (int i = 0; i < 4; ++i) {
          const int L = wave * 4 + i;
          const int brow = L * 16 + srow;
          const int bsc = sch ^ ((brow >> 1) & 3);
          gl_lds16(Wb + (size_t)brow * EMB + kn + bsc * 8, &Bn[L * 512]);
        }
      }
      short8 af[4], bf[4];
#pragma unroll
      for (int m = 0; m < 4; ++m) {
        const int row = m * 16 + l15;
        af[m] = *(const short8*)&Ac[row * 32 + ((quad ^ ((row >> 1) & 3)) << 3)];
      }
#pragma unroll
      for (int n = 0; n < 4; ++n) {
        const int row = wave * 64 + n * 16 + l15;
        bf[n] = *(const short8*)&Bc[row * 32 + ((quad ^ ((row >> 1) & 3)) << 3)];
      }
      __builtin_amdgcn_s_setprio(1);
#pragma unroll
      for (int n = 0; n < 4; ++n)
#pragma unroll
        for (int m = 0; m < 4; ++m)
          qacc[m][n] = __builtin_amdgcn_mfma_f32_16x16x32_bf16(af[m], bf[n], qacc[m][n], 0, 0, 0);
      __builtin_amdgcn_s_setprio(0);
      __syncthreads();  // all reads of Ac/Bc done; next DMA (into An/Bn) drained
      p ^= 1;
    }

    // epilogue -> Qs (scale 1/16, + bias); Qs aliases the dbuf region
#pragma unroll
    for (int n = 0; n < 4; ++n) {
      const int col = wave * 64 + n * 16 + l15;
      const float bqv = loadf(bq, hh * 256 + col, f32);
#pragma unroll
      for (int m = 0; m < 4; ++m)
#pragma unroll
        for (int r = 0; r < 4; ++r)
          Qs[(m * 16 + quad * 4 + r) * 264 + col] = f2b((qacc[m][n][r] + bqv) * 0.0625f);
    }
    __syncthreads();
#pragma unroll
    for (int ks = 0; ks < 8; ++ks)
      qf[ks] = *(const short8*)&Qs[(wave * 16 + l15) * 264 + ks * 32 + quad * 8];
    __syncthreads();  // qf reads done before phase A staging overwrites Qs
  }

  // ---------------- Phase A: flash over keys ------------------------------
  const unsigned short* Kp = Kb + (size_t)bh * NS * DKV;
  const unsigned short* Vp = Vtb + (size_t)bh * DKV * NS;

  floatx4 oacc[4][4];     // [row-tile m][d-subtile ct] for this wave's d stripe
  for (int m = 0; m < 4; ++m)
    for (int ct = 0; ct < 4; ++ct) oacc[m][ct] = (floatx4)0.0f;
  float l_part = 0.f;     // sum over keys for q-row (wave*16 + l15), this quad's share

  // gl_lds geometry (per lane, loop-invariant):
  const int krow_in = lane >> 5;        // 0..1 within a 2-keyrow 1KB load
  const int kc16 = lane & 31;           // 16B chunk within 512B key row
  const int vrow_in = lane >> 2;        // 0..15 within a 16-drow 1KB load
  const int vc = lane & 3;              // 16B chunk within 64B d row

  // prologue: stage K(0)->Ks0, K(1)->Ks1, V(0)->Vts
#pragma unroll
  for (int i = 0; i < 4; ++i) {
    const int L = wave * 4 + i;                  // 0..15
    const int krow = L * 2 + krow_in;
    const int kg = kc16 ^ (krow & 7);
    gl_lds16(Kp + (size_t)krow * DKV + kg * 8, &smem[L * 512]);
    gl_lds16(Kp + (size_t)(32 + krow) * DKV + kg * 8, &smem[8192 + L * 512]);
    const int vd = L * 16 + vrow_in;
    const int vg = vc ^ ((vd >> 1) & 3);
    gl_lds16(Vp + (size_t)vd * NS + vg * 8, &Vts[L * 512]);
  }
  __syncthreads();  // drain: K(0), K(1), V(0) ready

  for (int j0 = 0; j0 < NS; j0 += 32) {
    unsigned short* Kcur = smem + (((j0 >> 5) & 1) ? 8192 : 0);

    // S^T = K Q^T (swapped operands): D col = l15 = q-row, D row = key.
    floatx4 sacc[2];
    sacc[0] = (floatx4)0.0f; sacc[1] = (floatx4)0.0f;
    __builtin_amdgcn_s_setprio(1);
#pragma unroll
    for (int ks = 0; ks < 8; ++ks)
#pragma unroll
      for (int ct = 0; ct < 2; ++ct) {
        short8 kfr = *(const short8*)&Kcur[(ct * 16 + l15) * 256 +
                                           (((ks * 4 + quad) ^ (l15 & 7)) << 3)];
        sacc[ct] = __builtin_amdgcn_mfma_f32_16x16x32_bf16(kfr, qf[ks], sacc[ct], 0, 0, 0);
      }
    __builtin_amdgcn_s_setprio(0);

    // p = exp(s) unnormalized; pack 4 consecutive keys -> one b64 write
#pragma unroll
    for (int ct = 0; ct < 2; ++ct) {
      float p0 = __expf(sacc[ct][0]);
      float p1 = __expf(sacc[ct][1]);
      float p2 = __expf(sacc[ct][2]);
      float p3 = __expf(sacc[ct][3]);
      l_part += (p0 + p1) + (p2 + p3);
      uint2 pk;
      pk.x = (uint32_t)f2b(p0) | ((uint32_t)f2b(p1) << 16);
      pk.y = (uint32_t)f2b(p2) | ((uint32_t)f2b(p3) << 16);
      *(uint2*)&Ps[(wave * 16 + l15) * 40 + ct * 16 + quad * 4] = pk;
    }
    __syncthreads();  // B1: Ps visible; QK reads of Kcur done; drains V(t) AND K(t+1)

    // issue K(t+2) into the buffer QK(t) just finished (drained at B1(t+1))
    if (j0 + 64 < NS) {
#pragma unroll
      for (int i = 0; i < 4; ++i) {
        const int L = wave * 4 + i;
        const int krow = L * 2 + krow_in;
        const int kg = kc16 ^ (krow & 7);
        gl_lds16(Kp + (size_t)(j0 + 64 + krow) * DKV + kg * 8, &Kcur[L * 512]);
      }
    }

    // P @ V: all 64 rows x this wave's 64-d stripe
    short8 pa[4];
#pragma unroll
    for (int m = 0; m < 4; ++m)
      pa[m] = *(const short8*)&Ps[(m * 16 + l15) * 40 + quad * 8];
    __builtin_amdgcn_s_setprio(1);
#pragma unroll
    for (int ct = 0; ct < 4; ++ct) {
      const int rv = wave * 64 + ct * 16 + l15;
      short8 vb = *(const short8*)&Vts[rv * 32 + ((quad ^ ((rv >> 1) & 3)) << 3)];
#pragma unroll
      for (int m = 0; m < 4; ++m)
        oacc[m][ct] = __builtin_amdgcn_mfma_f32_16x16x32_bf16(pa[m], vb, oacc[m][ct], 0, 0, 0);
    }
    __builtin_amdgcn_s_setprio(0);
    // B2: RAW barrier — no vmem drain. All waves' PV/Ps ds_reads are complete
    // by arrival (MFMA register dep); in-flight K(t+2) targets an unread buf.
    __builtin_amdgcn_s_barrier();

    // issue V(t+1) -> drained at B1(t+1), flies under next QK+softmax
    if (j0 + 32 < NS) {
#pragma unroll
      for (int i = 0; i < 4; ++i) {
        const int L = wave * 4 + i;
        const int vd = L * 16 + vrow_in;
        const int vg = vc ^ ((vd >> 1) & 3);
        gl_lds16(Vp + (size_t)vd * NS + j0 + 32 + vg * 8, &Vts[L * 512]);
      }
    }
  }

  // l reduce: lane has partial sum for q-row wave*16+l15; sum across quads
  float l_r = l_part;
  l_r += __shfl_xor(l_r, 16);
  l_r += __shfl_xor(l_r, 32);

  __syncthreads();  // full sync+drain (no DMA outstanding: issues guarded)
  float* Lsf = (float*)smem;  // [64] f32, aliases Ks0
  if (quad == 0) Lsf[wave * 16 + l15] = l_r;
  __syncthreads();

#pragma unroll
  for (int m = 0; m < 4; ++m) {
    float linv[4];
#pragma unroll
    for (int r = 0; r < 4; ++r) linv[r] = 1.0f / Lsf[m * 16 + quad * 4 + r];
#pragma unroll
    for (int ct = 0; ct < 4; ++ct) {
      const int col = hh * DKV + wave * 64 + ct * 16 + l15;
#pragma unroll
      for (int r = 0; r < 4; ++r) {
        const int n = q0 + m * 16 + quad * 4 + r;
        Ob[((size_t)(bb * NS + n)) * EMB + col] = f2b(oacc[m][ct][r] * linv[r]);
      }
    }
  }
}

// ---------------------------------------------------------------------------
// Output projection (padded LDS, T14-pipelined reg staging), (256,3).
// ---------------------------------------------------------------------------
__global__ __launch_bounds__(256, 3) void out_gemm(
    const unsigned short* __restrict__ A, const unsigned short* __restrict__ W0T,
    const void* __restrict__ b0, void* __restrict__ out,
    const int* __restrict__ flag) {
  __shared__ __align__(16) unsigned short As[128 * 40];
  __shared__ __align__(16) unsigned short Bs[128 * 40];
  const int f32 = *flag;
  const int tid = threadIdx.x;
  const int wave = tid >> 6, lane = tid & 63, quad = lane >> 4, l15 = lane & 15;
  const int wm = wave >> 1, wn = wave & 1;
  const int row0 = blockIdx.y * 128;
  const int c0 = blockIdx.x * 128;

  floatx4 acc[4][4];
  for (int m = 0; m < 4; ++m)
    for (int n = 0; n < 4; ++n) acc[m][n] = (floatx4)0.0f;

  const unsigned short* Ab = A + (size_t)row0 * EMB;
  const unsigned short* Bb = W0T + (size_t)c0 * EMB;

  short8 va[2], vb[2];
#pragma unroll
  for (int i = 0; i < 2; ++i) {           // prologue: k0 = 0
    int idx = i * 256 + tid;
    int r = idx >> 2, kp = (idx & 3) << 3;
    va[i] = *(const short8*)(Ab + (size_t)r * EMB + kp);
    vb[i] = *(const short8*)(Bb + (size_t)r * EMB + kp);
  }

  for (int k0 = 0; k0 < EMB; k0 += 32) {
    __syncthreads();
#pragma unroll
    for (int i = 0; i < 2; ++i) {
      int idx = i * 256 + tid;
      *(short8*)&As[(idx >> 2) * 40 + (idx & 3) * 8] = va[i];
      *(short8*)&Bs[(idx >> 2) * 40 + (idx & 3) * 8] = vb[i];
    }
    if (k0 + 32 < EMB) {                  // issue next-tile loads
      const int kn = k0 + 32;
#pragma unroll
      for (int i = 0; i < 2; ++i) {
        int idx = i * 256 + tid;
        int r = idx >> 2, kp = (idx & 3) << 3;
        va[i] = *(const short8*)(Ab + (size_t)r * EMB + kn + kp);
        vb[i] = *(const short8*)(Bb + (size_t)r * EMB + kn + kp);
      }
    }
    __syncthreads();
    short8 af[4], bf[4];
#pragma unroll
    for (int m = 0; m < 4; ++m)
      af[m] = *(const short8*)&As[(wm * 64 + m * 16 + l15) * 40 + quad * 8];
#pragma unroll
    for (int n = 0; n < 4; ++n)
      bf[n] = *(const short8*)&Bs[(wn * 64 + n * 16 + l15) * 40 + quad * 8];
    __builtin_amdgcn_s_setprio(1);
#pragma unroll
    for (int n = 0; n < 4; ++n)
#pragma unroll
      for (int m = 0; m < 4; ++m)
        acc[m][n] = __builtin_amdgcn_mfma_f32_16x16x32_bf16(af[m], bf[n], acc[m][n], 0, 0, 0);
    __builtin_amdgcn_s_setprio(0);
  }

#pragma unroll
  for (int n = 0; n < 4; ++n) {
    const int col = c0 + wn * 64 + n * 16 + l15;
    const float bvv = loadf(b0, col, f32);
#pragma unroll
    for (int m = 0; m < 4; ++m) {
      const int rbase = row0 + wm * 64 + m * 16 + quad * 4;
#pragma unroll
      for (int r = 0; r < 4; ++r) {
        const float v = acc[m][n][r] + bvv;
        const size_t idx = (size_t)(rbase + r) * EMB + col;
        if (f32) ((float*)out)[idx] = v;
        else     ((unsigned short*)out)[idx] = f2b(v);
      }
    }
  }
}

// ---------------------------------------------------------------------------
extern "C" void kernel_launch(void* const* d_in, const int* in_sizes, int n_in,
                              void* d_out, int out_size, void* d_ws, size_t ws_size,
                              hipStream_t stream) {
  const void* x  = d_in[0];
  const void* Wq = d_in[1];
  const void* bq = d_in[2];
  const void* Wk = d_in[3];
  const void* bk = d_in[4];
  const void* Wv = d_in[5];
  const void* bv = d_in[6];
  const void* W0 = d_in[7];
  const void* b0 = d_in[8];

  unsigned short* ws = (unsigned short*)d_ws;
  const size_t SZ = (size_t)NB * 3 * NS * DKV;   // 12,582,912 elems
  unsigned short* Kb  = (unsigned short*)d_out;  // K parked in d_out until out_gemm
  unsigned short* Vtb = ws;                      // 25.2 MB
  unsigned short* Ob  = ws + SZ;                 // 25.2 MB
  unsigned short* WT  = ws + 2 * SZ;             // 3.5 MB
  unsigned short* W0T = WT + (size_t)2304 * EMB; // 1.2 MB
  int* flag = (int*)(W0T + (size_t)EMB * EMB);   // flag[0]=dtype, flag[1]=0
  unsigned short* Xb = (unsigned short*)((char*)flag + 16);  // 25.2 MB (optional)

  // need: base layout + 16B flags + SZ bf16 for Xb
  const size_t need = ((size_t)3 * SZ + (size_t)2304 * EMB + (size_t)EMB * EMB) * 2 + 16;
  const int use_xb = (ws_size >= need) ? 1 : 0;

  const void* x_gemm = use_xb ? (const void*)Xb : x;
  const int* xflag   = use_xb ? (flag + 1) : flag;

  detect_kernel<<<dim3(1), dim3(256), 0, stream>>>((const unsigned short*)x, flag);
  repack_all<<<dim3(3840), dim3(256), 0, stream>>>(Wq, Wk, Wv, W0, x, WT, W0T, Xb, flag, use_xb);
  kv_gemm<<<dim3(6, 128), dim3(256), 0, stream>>>(x_gemm, WT, bk, bv, Kb, Vtb, xflag, flag);
  flash_fused<<<dim3(24, 32), dim3(256), 0, stream>>>(x_gemm, WT, bq, Kb, Vtb, Ob, xflag, flag);
  out_gemm<<<dim3(6, 128), dim3(256), 0, stream>>>(Ob, W0T, b0, d_out, flag);
}

// Round 14
// 359.291 us; speedup vs baseline: 1.1046x; 1.1046x over previous
//
#include <hip/hip_runtime.h>
#include <stdint.h>

typedef __attribute__((ext_vector_type(8))) short short8;
typedef __attribute__((ext_vector_type(4))) float floatx4;

#define EMB 768
#define DKV 256
#define NB  8
#define NS  2048

__device__ __forceinline__ float b2f(unsigned short u) {
  union { unsigned int i; float f; } v; v.i = ((unsigned int)u) << 16; return v.f;
}
__device__ __forceinline__ unsigned short f2b(float f) {
  union { float f; unsigned int i; } v; v.f = f;
  return (unsigned short)((v.i + 0x7FFFu + ((v.i >> 16) & 1u)) >> 16);
}

__device__ __forceinline__ short8 load8x(const void* p, size_t e, int f32) {
  short8 r;
  if (f32) {
    const float* f = (const float*)p + e;
    float4 a = *(const float4*)f;
    float4 b = *(const float4*)(f + 4);
    r[0] = (short)f2b(a.x); r[1] = (short)f2b(a.y);
    r[2] = (short)f2b(a.z); r[3] = (short)f2b(a.w);
    r[4] = (short)f2b(b.x); r[5] = (short)f2b(b.y);
    r[6] = (short)f2b(b.z); r[7] = (short)f2b(b.w);
  } else {
    r = *(const short8*)((const unsigned short*)p + e);
  }
  return r;
}
__device__ __forceinline__ float loadf(const void* p, size_t e, int f32) {
  return f32 ? ((const float*)p)[e] : b2f(((const unsigned short*)p)[e]);
}

// Async global->LDS DMA, 16B per lane; LDS dest = wave-uniform base + lane*16.
__device__ __forceinline__ void gl_lds16(const void* g, void* l) {
  __builtin_amdgcn_global_load_lds(
      (const __attribute__((address_space(1))) void*)g,
      (__attribute__((address_space(3))) void*)l, 16, 0, 0);
}

// ---------------------------------------------------------------------------
__global__ __launch_bounds__(256) void detect_kernel(
    const unsigned short* __restrict__ x, int* __restrict__ flag) {
  __shared__ int cnt;
  if (threadIdx.x == 0) cnt = 0;
  __syncthreads();
  int bad = 0;
  for (int i = threadIdx.x; i < 1024; i += 256) {
    float v = b2f(x[i]);
    if (!(fabsf(v) <= 1e4f)) bad++;
  }
  atomicAdd(&cnt, bad);
  __syncthreads();
  if (threadIdx.x == 0) {
    flag[0] = (cnt > 16) ? 1 : 0;   // real dtype flag (biases, outputs)
    flag[1] = 0;                    // constant bf16 flag for converted-X path
  }
}

// ---------------------------------------------------------------------------
// Merged prep kernel, 1D grid of 3840 blocks:
//   [0,1728)    WT tile transposes: WT[slab*256+d][k] = W[t][h][k][d]
//   [1728,2304) W0T tile transposes
//   [2304,3840) X -> bf16 conversion into Xb (only if do_x)
// ---------------------------------------------------------------------------
__global__ __launch_bounds__(256) void repack_all(
    const void* __restrict__ Wq, const void* __restrict__ Wk,
    const void* __restrict__ Wv, const void* __restrict__ W0,
    const void* __restrict__ X,
    unsigned short* __restrict__ WT, unsigned short* __restrict__ W0T,
    unsigned short* __restrict__ Xb,
    const int* __restrict__ flag, int do_x) {
  __shared__ unsigned short tile[32][33];
  const int f32 = *flag;
  const int tid = threadIdx.x;
  const int b = blockIdx.x;

  if (b < 1728) {
    const int slab = b / 192;            // 0..8
    const int rem = b - slab * 192;
    const int k0 = (rem % 24) * 32, d0 = (rem / 24) * 32;
    const int t = slab / 3, h = slab - t * 3;
    const void* Wsrc = (t == 0) ? Wq : ((t == 1) ? Wk : Wv);
#pragma unroll
    for (int rr = 0; rr < 4; ++rr) {
      int ki = rr * 8 + (tid >> 5), di = tid & 31;
      tile[ki][di] = f2b(loadf(Wsrc, (size_t)(h * EMB + k0 + ki) * DKV + d0 + di, f32));
    }
    __syncthreads();
#pragma unroll
    for (int rr = 0; rr < 4; ++rr) {
      int di = rr * 8 + (tid >> 5), ki = tid & 31;
      WT[(size_t)(slab * 256 + d0 + di) * EMB + k0 + ki] = tile[ki][di];
    }
  } else if (b < 2304) {
    const int bb = b - 1728;             // 0..575
    const int k0 = (bb % 24) * 32, o0 = (bb / 24) * 32;
#pragma unroll
    for (int rr = 0; rr < 4; ++rr) {
      int ki = rr * 8 + (tid >> 5), oi = tid & 31;
      tile[ki][oi] = f2b(loadf(W0, (size_t)(k0 + ki) * EMB + o0 + oi, f32));
    }
    __syncthreads();
#pragma unroll
    for (int rr = 0; rr < 4; ++rr) {
      int oi = rr * 8 + (tid >> 5), ki = tid & 31;
      W0T[(size_t)(o0 + oi) * EMB + k0 + ki] = tile[ki][oi];
    }
  } else {
    if (!do_x) return;
    const int bb = b - 2304;             // 0..1535; 1536*1024 short8 = 12.58M elems
#pragma unroll
    for (int i = 0; i < 4; ++i) {
      size_t e = ((size_t)bb * 1024 + i * 256 + tid) * 8;
      short8 v = load8x(X, e, f32);
      *(short8*)&Xb[e] = v;
    }
  }
}

// ---------------------------------------------------------------------------
// Fused K+V projection GEMM, 128 rows x (128 K-cols + 128 V-cols),
// T14-pipelined reg staging (r8-measured best; r9's gload_lds was neutral).
// ---------------------------------------------------------------------------
__global__ __launch_bounds__(256, 2) void kv_gemm(
    const void* __restrict__ Xs, const unsigned short* __restrict__ WT,
    const void* __restrict__ bk, const void* __restrict__ bv,
    unsigned short* __restrict__ Kb, unsigned short* __restrict__ Vtb,
    const int* __restrict__ xflag, const int* __restrict__ dflag) {
  __shared__ __align__(16) unsigned short As[128 * 40];
  __shared__ __align__(16) unsigned short BsK[128 * 40];
  __shared__ __align__(16) unsigned short BsV[128 * 40];
  const int xf32 = *xflag;
  const int f32 = *dflag;
  const int tid = threadIdx.x;
  const int wave = tid >> 6, lane = tid & 63, quad = lane >> 4, l15 = lane & 15;
  const int wm = wave >> 1, wn = wave & 1;
  const int row0 = blockIdx.y * 128;
  const int cb = blockIdx.x * 128;       // 0..640, col offset within each slab

  floatx4 accK[4][4], accV[4][4];
  for (int m = 0; m < 4; ++m)
    for (int n = 0; n < 4; ++n) { accK[m][n] = (floatx4)0.0f; accV[m][n] = (floatx4)0.0f; }

  const size_t arow0 = (size_t)row0 * EMB;
  const unsigned short* BbK = WT + (size_t)(768 + cb) * EMB;
  const unsigned short* BbV = WT + (size_t)(1536 + cb) * EMB;

  short8 va[2], vk[2], vv[2];
#pragma unroll
  for (int i = 0; i < 2; ++i) {           // prologue: k0 = 0
    int idx = i * 256 + tid;
    int r = idx >> 2, kp = (idx & 3) << 3;
    va[i] = load8x(Xs, arow0 + (size_t)r * EMB + kp, xf32);
    vk[i] = *(const short8*)(BbK + (size_t)r * EMB + kp);
    vv[i] = *(const short8*)(BbV + (size_t)r * EMB + kp);
  }

  for (int k0 = 0; k0 < EMB; k0 += 32) {
    __syncthreads();
#pragma unroll
    for (int i = 0; i < 2; ++i) {
      int idx = i * 256 + tid;
      int off = (idx >> 2) * 40 + (idx & 3) * 8;
      *(short8*)&As[off] = va[i];
      *(short8*)&BsK[off] = vk[i];
      *(short8*)&BsV[off] = vv[i];
    }
    if (k0 + 32 < EMB) {                  // issue next-tile loads
      const int kn = k0 + 32;
#pragma unroll
      for (int i = 0; i < 2; ++i) {
        int idx = i * 256 + tid;
        int r = idx >> 2, kp = (idx & 3) << 3;
        va[i] = load8x(Xs, arow0 + (size_t)r * EMB + kn + kp, xf32);
        vk[i] = *(const short8*)(BbK + (size_t)r * EMB + kn + kp);
        vv[i] = *(const short8*)(BbV + (size_t)r * EMB + kn + kp);
      }
    }
    __syncthreads();
    short8 af[4], bk4[4], bv4[4];
#pragma unroll
    for (int m = 0; m < 4; ++m)
      af[m] = *(const short8*)&As[(wm * 64 + m * 16 + l15) * 40 + quad * 8];
#pragma unroll
    for (int n = 0; n < 4; ++n) {
      bk4[n] = *(const short8*)&BsK[(wn * 64 + n * 16 + l15) * 40 + quad * 8];
      bv4[n] = *(const short8*)&BsV[(wn * 64 + n * 16 + l15) * 40 + quad * 8];
    }
    __builtin_amdgcn_s_setprio(1);
#pragma unroll
    for (int n = 0; n < 4; ++n)
#pragma unroll
      for (int m = 0; m < 4; ++m) {
        accK[m][n] = __builtin_amdgcn_mfma_f32_16x16x32_bf16(af[m], bk4[n], accK[m][n], 0, 0, 0);
        accV[m][n] = __builtin_amdgcn_mfma_f32_16x16x32_bf16(af[m], bv4[n], accV[m][n], 0, 0, 0);
      }
    __builtin_amdgcn_s_setprio(0);
  }

  const int h = cb >> 8;
  const int dbase = cb & 255;

  // K epilogue: [bh][n][d]
#pragma unroll
  for (int n = 0; n < 4; ++n) {
    const int cc = wn * 64 + n * 16 + l15;
    const float bvv = loadf(bk, h * 256 + dbase + cc, f32);
    const int d = dbase + cc;
#pragma unroll
    for (int m = 0; m < 4; ++m) {
      const int rbase = row0 + wm * 64 + m * 16 + quad * 4;
#pragma unroll
      for (int r = 0; r < 4; ++r) {
        const int row = rbase + r;
        const int bb = row >> 11, nn = row & 2047;
        Kb[((size_t)(bb * 3 + h) * 2048 + nn) * 256 + d] = f2b(accK[m][n][r] + bvv);
      }
    }
  }
  // V epilogue: transposed [bh][d][n]
#pragma unroll
  for (int n = 0; n < 4; ++n) {
    const int cc = wn * 64 + n * 16 + l15;
    const float bvv = loadf(bv, h * 256 + dbase + cc, f32);
    const int d = dbase + cc;
#pragma unroll
    for (int m = 0; m < 4; ++m) {
      const int rbase = row0 + wm * 64 + m * 16 + quad * 4;
      const int bb = rbase >> 11, nn = rbase & 2047;
      const size_t base = ((size_t)(bb * 3 + h) * 256 + d) * 2048 + nn;
      uint2 val;
      val.x = (uint32_t)f2b(accV[m][n][0] + bvv) | ((uint32_t)f2b(accV[m][n][1] + bvv) << 16);
      val.y = (uint32_t)f2b(accV[m][n][2] + bvv) | ((uint32_t)f2b(accV[m][n][3] + bvv) << 16);
      *(uint2*)(Vtb + base) = val;
    }
  }
}

// ---------------------------------------------------------------------------
// Fused Q-projection + flash attention, 64 q-rows/block.
// Phase Q: gl_lds double-buffered ping-pong (A 4KBx2 + B 16KBx2 = 40KB),
//   1 barrier/K-step, zero staging VALU; both-sides XOR swizzle.
// Phase A: gl_lds + ping-pong split prefetch (single Ks; 40KB total keeps
//   3 blocks/CU — r13 measured: 53KB drops to 2 blocks/CU, -50us).
// ---------------------------------------------------------------------------
__global__ __launch_bounds__(256, 3) void flash_fused(
    const void* __restrict__ Xs, const unsigned short* __restrict__ WT,
    const void* __restrict__ bq,
    const unsigned short* __restrict__ Kb, const unsigned short* __restrict__ Vtb,
    unsigned short* __restrict__ Ob,
    const int* __restrict__ xflag, const int* __restrict__ dflag) {
  __shared__ __align__(16) unsigned short smem[20480];  // 40 KB
  // phase Q dbuf: A0 0..2048, A1 2048..4096, B0 4096..12288, B1 12288..20480
  unsigned short* Qs  = smem;           // phase Q epilogue: [64][264] (0..16896) ALIASES bufs
  unsigned short* Ks  = smem;           // phase A: [32][256] linear swz (0..8192)
  unsigned short* Vts = smem + 8192;    // phase A: [256][32] linear swz (8192..16384)
  unsigned short* Ps  = smem + 16384;   // phase A: [64][40]  (16384..18944)

  const int xf32 = *xflag;
  const int f32 = *dflag;
  const int tid = threadIdx.x;
  const int wave = tid >> 6, lane = tid & 63, quad = lane >> 4, l15 = lane & 15;
  const int bh = blockIdx.x;            // bh fastest; 24%8==0 -> per-bh K/V XCD-local
  const int bb = bh / 3, hh = bh - bb * 3;
  const int q0 = blockIdx.y * 64;

  short8 qf[8];

  // ---------------- Phase Q: project one 64x256 Q strip --------------------
  {
    const size_t xrow0 = (size_t)bb * NS + q0;
    floatx4 qacc[4][4];
    for (int m = 0; m < 4; ++m)
      for (int n = 0; n < 4; ++n) qacc[m][n] = (floatx4)0.0f;

    const int srow = lane >> 2;          // 0..15 within a 16-row 1KB segment
    const int sch  = lane & 3;           // physical 16B chunk within 64B row
    const unsigned short* Wb = WT + (size_t)hh * 256 * EMB;

    // prologue: stage k0 = 0 into buffer 0
    {
      if (!xf32) {
        const int arow = wave * 16 + srow;
        const int asc = sch ^ ((arow >> 1) & 3);
        gl_lds16((const unsigned short*)Xs + (xrow0 + arow) * EMB + asc * 8,
                 &smem[wave * 512]);
      } else {
        int row = tid >> 2, pch = tid & 3;
        int gsc = pch ^ ((row >> 1) & 3);
        short8 v = load8x(Xs, (xrow0 + row) * EMB + gsc * 8, 1);
        *(short8*)&smem[row * 32 + pch * 8] = v;
      }
#pragma unroll
      for (int i = 0; i < 4; ++i) {
        const int L = wave * 4 + i;
        const int brow = L * 16 + srow;
        const int bsc = sch ^ ((brow >> 1) & 3);
        gl_lds16(Wb + (size_t)brow * EMB + bsc * 8, &smem[4096 + L * 512]);
      }
    }
    __syncthreads();   // buffer 0 ready

    int p = 0;
    for (int k0 = 0; k0 < EMB; k0 += 32) {
      unsigned short* Ac = smem + (p ? 2048 : 0);
      unsigned short* Bc = smem + 4096 + (p ? 8192 : 0);
      if (k0 + 32 < EMB) {               // stage next step into other buffer
        unsigned short* An = smem + (p ? 0 : 2048);
        unsigned short* Bn = smem + 4096 + (p ? 0 : 8192);
        const int kn = k0 + 32;
        if (!xf32) {
          const int arow = wave * 16 + srow;
          const int asc = sch ^ ((arow >> 1) & 3);
          gl_lds16((const unsigned short*)Xs + (xrow0 + arow) * EMB + kn + asc * 8,
                   &An[wave * 512]);
        } else {
          int row = tid >> 2, pch = tid & 3;
          int gsc = pch ^ ((row >> 1) & 3);
          short8 v = load8x(Xs, (xrow0 + row) * EMB + kn + gsc * 8, 1);
          *(short8*)&An[row * 32 + pch * 8] = v;
        }
#pragma unroll
        for (int i = 0; i < 4; ++i) {
          const int L = wave * 4 + i;
          const int brow = L * 16 + srow;
          const int bsc = sch ^ ((brow >> 1) & 3);
          gl_lds16(Wb + (size_t)brow * EMB + kn + bsc * 8, &Bn[L * 512]);
        }
      }
      short8 af[4], bf[4];
#pragma unroll
      for (int m = 0; m < 4; ++m) {
        const int row = m * 16 + l15;
        af[m] = *(const short8*)&Ac[row * 32 + ((quad ^ ((row >> 1) & 3)) << 3)];
      }
#pragma unroll
      for (int n = 0; n < 4; ++n) {
        const int row = wave * 64 + n * 16 + l15;
        bf[n] = *(const short8*)&Bc[row * 32 + ((quad ^ ((row >> 1) & 3)) << 3)];
      }
      __builtin_amdgcn_s_setprio(1);
#pragma unroll
      for (int n = 0; n < 4; ++n)
#pragma unroll
        for (int m = 0; m < 4; ++m)
          qacc[m][n] = __builtin_amdgcn_mfma_f32_16x16x32_bf16(af[m], bf[n], qacc[m][n], 0, 0, 0);
      __builtin_amdgcn_s_setprio(0);
      __syncthreads();  // all reads of Ac/Bc done; next DMA (into An/Bn) drained
      p ^= 1;
    }

    // epilogue -> Qs (scale 1/16, + bias); Qs aliases the dbuf region
#pragma unroll
    for (int n = 0; n < 4; ++n) {
      const int col = wave * 64 + n * 16 + l15;
      const float bqv = loadf(bq, hh * 256 + col, f32);
#pragma unroll
      for (int m = 0; m < 4; ++m)
#pragma unroll
        for (int r = 0; r < 4; ++r)
          Qs[(m * 16 + quad * 4 + r) * 264 + col] = f2b((qacc[m][n][r] + bqv) * 0.0625f);
    }
    __syncthreads();
#pragma unroll
    for (int ks = 0; ks < 8; ++ks)
      qf[ks] = *(const short8*)&Qs[(wave * 16 + l15) * 264 + ks * 32 + quad * 8];
    __syncthreads();  // qf reads done before phase A staging overwrites Qs
  }

  // ---------------- Phase A: flash over keys ------------------------------
  const unsigned short* Kp = Kb + (size_t)bh * NS * DKV;
  const unsigned short* Vp = Vtb + (size_t)bh * DKV * NS;

  floatx4 oacc[4][4];     // [row-tile m][d-subtile ct] for this wave's d stripe
  for (int m = 0; m < 4; ++m)
    for (int ct = 0; ct < 4; ++ct) oacc[m][ct] = (floatx4)0.0f;
  float l_part = 0.f;     // sum over keys for q-row (wave*16 + l15), this quad's share

  // gl_lds geometry (per lane, loop-invariant):
  const int krow_in = lane >> 5;        // 0..1 within a 2-keyrow 1KB load
  const int kc16 = lane & 31;           // 16B chunk within 512B key row
  const int vrow_in = lane >> 2;        // 0..15 within a 16-drow 1KB load
  const int vc = lane & 3;              // 16B chunk within 64B d row

  // prologue: stage tile 0 (Qs reads barriered above; Ks/Vts alias Qs)
#pragma unroll
  for (int i = 0; i < 4; ++i) {
    const int L = wave * 4 + i;                  // 0..15
    const int krow = L * 2 + krow_in;
    const int kg = kc16 ^ (krow & 7);
    gl_lds16(Kp + (size_t)krow * DKV + kg * 8, &Ks[L * 512]);
    const int vd = L * 16 + vrow_in;
    const int vg = vc ^ ((vd >> 1) & 3);
    gl_lds16(Vp + (size_t)vd * NS + vg * 8, &Vts[L * 512]);
  }
  __syncthreads();  // drain: tile 0 ready

  for (int j0 = 0; j0 < NS; j0 += 32) {
    // S^T = K Q^T (swapped operands): D col = l15 = q-row, D row = key.
    floatx4 sacc[2];
    sacc[0] = (floatx4)0.0f; sacc[1] = (floatx4)0.0f;
    __builtin_amdgcn_s_setprio(1);
#pragma unroll
    for (int ks = 0; ks < 8; ++ks)
#pragma unroll
      for (int ct = 0; ct < 2; ++ct) {
        short8 kfr = *(const short8*)&Ks[(ct * 16 + l15) * 256 +
                                         (((ks * 4 + quad) ^ (l15 & 7)) << 3)];
        sacc[ct] = __builtin_amdgcn_mfma_f32_16x16x32_bf16(kfr, qf[ks], sacc[ct], 0, 0, 0);
      }
    __builtin_amdgcn_s_setprio(0);

    // p = exp(s) unnormalized; pack 4 consecutive keys -> one b64 write
#pragma unroll
    for (int ct = 0; ct < 2; ++ct) {
      float p0 = __expf(sacc[ct][0]);
      float p1 = __expf(sacc[ct][1]);
      float p2 = __expf(sacc[ct][2]);
      float p3 = __expf(sacc[ct][3]);
      l_part += (p0 + p1) + (p2 + p3);
      uint2 pk;
      pk.x = (uint32_t)f2b(p0) | ((uint32_t)f2b(p1) << 16);
      pk.y = (uint32_t)f2b(p2) | ((uint32_t)f2b(p3) << 16);
      *(uint2*)&Ps[(wave * 16 + l15) * 40 + ct * 16 + quad * 4] = pk;
    }
    __syncthreads();  // B1: Ps visible; all QK reads of Ks done; drains V(t)

    // issue K(t+1) -> flies under PV
    if (j0 + 32 < NS) {
#pragma unroll
      for (int i = 0; i < 4; ++i) {
        const int L = wave * 4 + i;
        const int krow = L * 2 + krow_in;
        const int kg = kc16 ^ (krow & 7);
        gl_lds16(Kp + (size_t)(j0 + 32 + krow) * DKV + kg * 8, &Ks[L * 512]);
      }
    }

    // P @ V: all 64 rows x this wave's 64-d stripe
    short8 pa[4];
#pragma unroll
    for (int m = 0; m < 4; ++m)
      pa[m] = *(const short8*)&Ps[(m * 16 + l15) * 40 + quad * 8];
    __builtin_amdgcn_s_setprio(1);
#pragma unroll
    for (int ct = 0; ct < 4; ++ct) {
      const int rv = wave * 64 + ct * 16 + l15;
      short8 vb = *(const short8*)&Vts[rv * 32 + ((quad ^ ((rv >> 1) & 3)) << 3)];
#pragma unroll
      for (int m = 0; m < 4; ++m)
        oacc[m][ct] = __builtin_amdgcn_mfma_f32_16x16x32_bf16(pa[m], vb, oacc[m][ct], 0, 0, 0);
    }
    __builtin_amdgcn_s_setprio(0);
    __syncthreads();  // B2: PV reads done; drains K(t+1)

    // issue V(t+1) -> flies under next tile's QK+softmax
    if (j0 + 32 < NS) {
#pragma unroll
      for (int i = 0; i < 4; ++i) {
        const int L = wave * 4 + i;
        const int vd = L * 16 + vrow_in;
        const int vg = vc ^ ((vd >> 1) & 3);
        gl_lds16(Vp + (size_t)vd * NS + j0 + 32 + vg * 8, &Vts[L * 512]);
      }
    }
  }

  // l reduce: lane has partial sum for q-row wave*16+l15; sum across quads
  float l_r = l_part;
  l_r += __shfl_xor(l_r, 16);
  l_r += __shfl_xor(l_r, 32);

  __syncthreads();  // all waves past last B2; no outstanding DMA (guarded)
  float* Lsf = (float*)smem;  // [64] f32, aliases Ks
  if (quad == 0) Lsf[wave * 16 + l15] = l_r;
  __syncthreads();

#pragma unroll
  for (int m = 0; m < 4; ++m) {
    float linv[4];
#pragma unroll
    for (int r = 0; r < 4; ++r) linv[r] = 1.0f / Lsf[m * 16 + quad * 4 + r];
#pragma unroll
    for (int ct = 0; ct < 4; ++ct) {
      const int col = hh * DKV + wave * 64 + ct * 16 + l15;
#pragma unroll
      for (int r = 0; r < 4; ++r) {
        const int n = q0 + m * 16 + quad * 4 + r;
        Ob[((size_t)(bb * NS + n)) * EMB + col] = f2b(oacc[m][ct][r] * linv[r]);
      }
    }
  }
}

// ---------------------------------------------------------------------------
// Output projection (padded LDS, T14-pipelined reg staging), (256,3).
// ---------------------------------------------------------------------------
__global__ __launch_bounds__(256, 3) void out_gemm(
    const unsigned short* __restrict__ A, const unsigned short* __restrict__ W0T,
    const void* __restrict__ b0, void* __restrict__ out,
    const int* __restrict__ flag) {
  __shared__ __align__(16) unsigned short As[128 * 40];
  __shared__ __align__(16) unsigned short Bs[128 * 40];
  const int f32 = *flag;
  const int tid = threadIdx.x;
  const int wave = tid >> 6, lane = tid & 63, quad = lane >> 4, l15 = lane & 15;
  const int wm = wave >> 1, wn = wave & 1;
  const int row0 = blockIdx.y * 128;
  const int c0 = blockIdx.x * 128;

  floatx4 acc[4][4];
  for (int m = 0; m < 4; ++m)
    for (int n = 0; n < 4; ++n) acc[m][n] = (floatx4)0.0f;

  const unsigned short* Ab = A + (size_t)row0 * EMB;
  const unsigned short* Bb = W0T + (size_t)c0 * EMB;

  short8 va[2], vb[2];
#pragma unroll
  for (int i = 0; i < 2; ++i) {           // prologue: k0 = 0
    int idx = i * 256 + tid;
    int r = idx >> 2, kp = (idx & 3) << 3;
    va[i] = *(const short8*)(Ab + (size_t)r * EMB + kp);
    vb[i] = *(const short8*)(Bb + (size_t)r * EMB + kp);
  }

  for (int k0 = 0; k0 < EMB; k0 += 32) {
    __syncthreads();
#pragma unroll
    for (int i = 0; i < 2; ++i) {
      int idx = i * 256 + tid;
      *(short8*)&As[(idx >> 2) * 40 + (idx & 3) * 8] = va[i];
      *(short8*)&Bs[(idx >> 2) * 40 + (idx & 3) * 8] = vb[i];
    }
    if (k0 + 32 < EMB) {                  // issue next-tile loads
      const int kn = k0 + 32;
#pragma unroll
      for (int i = 0; i < 2; ++i) {
        int idx = i * 256 + tid;
        int r = idx >> 2, kp = (idx & 3) << 3;
        va[i] = *(const short8*)(Ab + (size_t)r * EMB + kn + kp);
        vb[i] = *(const short8*)(Bb + (size_t)r * EMB + kn + kp);
      }
    }
    __syncthreads();
    short8 af[4], bf[4];
#pragma unroll
    for (int m = 0; m < 4; ++m)
      af[m] = *(const short8*)&As[(wm * 64 + m * 16 + l15) * 40 + quad * 8];
#pragma unroll
    for (int n = 0; n < 4; ++n)
      bf[n] = *(const short8*)&Bs[(wn * 64 + n * 16 + l15) * 40 + quad * 8];
    __builtin_amdgcn_s_setprio(1);
#pragma unroll
    for (int n = 0; n < 4; ++n)
#pragma unroll
      for (int m = 0; m < 4; ++m)
        acc[m][n] = __builtin_amdgcn_mfma_f32_16x16x32_bf16(af[m], bf[n], acc[m][n], 0, 0, 0);
    __builtin_amdgcn_s_setprio(0);
  }

#pragma unroll
  for (int n = 0; n < 4; ++n) {
    const int col = c0 + wn * 64 + n * 16 + l15;
    const float bvv = loadf(b0, col, f32);
#pragma unroll
    for (int m = 0; m < 4; ++m) {
      const int rbase = row0 + wm * 64 + m * 16 + quad * 4;
#pragma unroll
      for (int r = 0; r < 4; ++r) {
        const float v = acc[m][n][r] + bvv;
        const size_t idx = (size_t)(rbase + r) * EMB + col;
        if (f32) ((float*)out)[idx] = v;
        else     ((unsigned short*)out)[idx] = f2b(v);
      }
    }
  }
}

// ---------------------------------------------------------------------------
extern "C" void kernel_launch(void* const* d_in, const int* in_sizes, int n_in,
                              void* d_out, int out_size, void* d_ws, size_t ws_size,
                              hipStream_t stream) {
  const void* x  = d_in[0];
  const void* Wq = d_in[1];
  const void* bq = d_in[2];
  const void* Wk = d_in[3];
  const void* bk = d_in[4];
  const void* Wv = d_in[5];
  const void* bv = d_in[6];
  const void* W0 = d_in[7];
  const void* b0 = d_in[8];

  unsigned short* ws = (unsigned short*)d_ws;
  const size_t SZ = (size_t)NB * 3 * NS * DKV;   // 12,582,912 elems
  unsigned short* Kb  = (unsigned short*)d_out;  // K parked in d_out until out_gemm
  unsigned short* Vtb = ws;                      // 25.2 MB
  unsigned short* Ob  = ws + SZ;                 // 25.2 MB
  unsigned short* WT  = ws + 2 * SZ;             // 3.5 MB
  unsigned short* W0T = WT + (size_t)2304 * EMB; // 1.2 MB
  int* flag = (int*)(W0T + (size_t)EMB * EMB);   // flag[0]=dtype, flag[1]=0
  unsigned short* Xb = (unsigned short*)((char*)flag + 16);  // 25.2 MB (optional)

  // need: base layout + 16B flags + SZ bf16 for Xb
  const size_t need = ((size_t)3 * SZ + (size_t)2304 * EMB + (size_t)EMB * EMB) * 2 + 16;
  const int use_xb = (ws_size >= need) ? 1 : 0;

  const void* x_gemm = use_xb ? (const void*)Xb : x;
  const int* xflag   = use_xb ? (flag + 1) : flag;

  detect_kernel<<<dim3(1), dim3(256), 0, stream>>>((const unsigned short*)x, flag);
  repack_all<<<dim3(3840), dim3(256), 0, stream>>>(Wq, Wk, Wv, W0, x, WT, W0T, Xb, flag, use_xb);
  kv_gemm<<<dim3(6, 128), dim3(256), 0, stream>>>(x_gemm, WT, bk, bv, Kb, Vtb, xflag, flag);
  flash_fused<<<dim3(24, 32), dim3(256), 0, stream>>>(x_gemm, WT, bq, Kb, Vtb, Ob, xflag, flag);
  out_gemm<<<dim3(6, 128), dim3(256), 0, stream>>>(Ob, W0T, b0, d_out, flag);
}